// Round 1
// baseline (431.870 us; speedup 1.0000x reference)
//
#include <hip/hip_runtime.h>
#include <hip/hip_bf16.h>

// Problem constants
#define NA 8192      // oscillators in bank a (mask rows)
#define NB 8192      // oscillators in bank b (mask cols = GEMM K)
#define NBATCH 64
#define NC 128       // GEMM N: interleaved [cos_b, sin_b] columns, c=2b (cos), 2b+1 (sin)
#define BM 128       // output rows per block
#define WM 32        // output rows per wave (2 A-fragments of 16)
#define SPLITK 8
#define KCHUNK (NB / SPLITK)   // 1024

#define XT_BYTES (NC * NB * 2)            // 2 MiB bf16 Xt
#define CTR_OFF  XT_BYTES                 // 64 real + 64 imag f32 + count int
#define PPART_OFF (XT_BYTES + 4096)

typedef __bf16 bf16x8 __attribute__((ext_vector_type(8)));
typedef float  f32x4  __attribute__((ext_vector_type(4)));

// ---------------- prep: phases_b -> Xt[c][j], c=2b: cos, c=2b+1: sin (bf16) ----
__global__ __launch_bounds__(256) void prep_b_kernel(
    const float* __restrict__ pb, __hip_bfloat16* __restrict__ Xt)
{
    int tid = blockIdx.x * 256 + threadIdx.x;   // 0 .. NBATCH*NB-1
    int b = tid >> 13;          // / NB
    int j = tid & (NB - 1);
    float ph = pb[tid];
    float s, c;
    __sincosf(ph, &s, &c);
    Xt[(size_t)(2 * b) * NB + j]     = __float2bfloat16(c);
    Xt[(size_t)(2 * b + 1) * NB + j] = __float2bfloat16(s);
}

// ---------------- GEMM: P[i][c] = sum_j mask[i][j] * X[j][c] ------------------
// A-fragment (16x16x32 bf16): A[m=lane&15][k=quad*8+e]  -> direct global int4 loads
// B-fragment:                 B[k=quad*8+e][n=lane&15]  -> contiguous 16B from Xt
// C/D:                        col=lane&15, row=quad*4+reg (measured m89/m91)
__global__ __launch_bounds__(256, 2) void gemm_kernel(
    const int* __restrict__ mask, const __hip_bfloat16* __restrict__ Xtg,
    float* __restrict__ Ppart, int* __restrict__ count)
{
    const int tid  = threadIdx.x;
    const int wave = tid >> 6;
    const int lane = tid & 63;
    const int quad = lane >> 4;
    const int m    = lane & 15;
    const int itile = blockIdx.x;       // 0..63
    const int kc    = blockIdx.y;       // 0..SPLITK-1
    const int k0    = kc * KCHUNK;

    const int rowbase = itile * BM + wave * WM;   // this wave's first row
    const ushort* xt = reinterpret_cast<const ushort*>(Xtg);

    f32x4 acc[2][8];
#pragma unroll
    for (int f = 0; f < 2; ++f)
#pragma unroll
        for (int t = 0; t < 8; ++t)
            acc[f][t] = (f32x4){0.f, 0.f, 0.f, 0.f};

    int cnt = 0;

    for (int kk = k0; kk < k0 + KCHUNK; kk += 32) {
        const int kq = kk + quad * 8;

        bf16x8 a[2];
#pragma unroll
        for (int f = 0; f < 2; ++f) {
            const int4* p = reinterpret_cast<const int4*>(
                mask + (size_t)(rowbase + f * 16 + m) * NB + kq);
            int4 r0 = p[0];
            int4 r1 = p[1];
            cnt += r0.x + r0.y + r0.z + r0.w + r1.x + r1.y + r1.z + r1.w;
            uint4 u;
            u.x = (r0.x ? 0x3F80u : 0u) | (r0.y ? 0x3F800000u : 0u);
            u.y = (r0.z ? 0x3F80u : 0u) | (r0.w ? 0x3F800000u : 0u);
            u.z = (r1.x ? 0x3F80u : 0u) | (r1.y ? 0x3F800000u : 0u);
            u.w = (r1.z ? 0x3F80u : 0u) | (r1.w ? 0x3F800000u : 0u);
            a[f] = __builtin_bit_cast(bf16x8, u);
        }

#pragma unroll
        for (int t = 0; t < 8; ++t) {
            const bf16x8 bfrag = *reinterpret_cast<const bf16x8*>(
                xt + (size_t)(t * 16 + m) * NB + kq);
            acc[0][t] = __builtin_amdgcn_mfma_f32_16x16x32_bf16(a[0], bfrag, acc[0][t], 0, 0, 0);
            acc[1][t] = __builtin_amdgcn_mfma_f32_16x16x32_bf16(a[1], bfrag, acc[1][t], 0, 0, 0);
        }
    }

    // epilogue: write split-K partial tile
    float* pout = Ppart + (size_t)kc * NA * NC;
#pragma unroll
    for (int f = 0; f < 2; ++f)
#pragma unroll
        for (int t = 0; t < 8; ++t)
#pragma unroll
            for (int r = 0; r < 4; ++r) {
                int row = rowbase + f * 16 + quad * 4 + r;
                int col = t * 16 + m;
                pout[(size_t)row * NC + col] = acc[f][t][r];
            }

    // mask popcount: wave reduce then one atomic per wave
#pragma unroll
    for (int off = 32; off > 0; off >>= 1) cnt += __shfl_down(cnt, off);
    if (lane == 0) atomicAdd(count, cnt);
}

// ---------------- reduce: real/imag per batch ---------------------------------
// real_b = sum_i ca[b,i]*P[i,2b] + sa[b,i]*P[i,2b+1]
// imag_b = sum_i sa[b,i]*P[i,2b] - ca[b,i]*P[i,2b+1]
__global__ __launch_bounds__(256) void reduce_kernel(
    const float* __restrict__ pa, const float* __restrict__ Ppart,
    float* __restrict__ realg, float* __restrict__ imagg)
{
    const int t = threadIdx.x;
    const int c = t & 127;
    const int half = t >> 7;
    const int b = c >> 1;
    const int odd = c & 1;
    const int i0 = blockIdx.x * 32;

    float pacc = 0.f, qacc = 0.f;
    for (int i = i0 + half; i < i0 + 32; i += 2) {
        float v = 0.f;
#pragma unroll
        for (int kc = 0; kc < SPLITK; ++kc)
            v += Ppart[(size_t)kc * NA * NC + (size_t)i * NC + c];
        float ph = pa[b * NA + i];
        float sn, cs;
        __sincosf(ph, &sn, &cs);
        float yc = odd ? sn : cs;   // multiplies P for the real part
        float yo = odd ? cs : sn;   // cross term for the imag part
        pacc += yc * v;
        qacc += odd ? -(yo * v) : (yo * v);
    }

    __shared__ float red[2][256];
    red[0][t] = pacc;
    red[1][t] = qacc;
    __syncthreads();
    if (t < 128) {
        red[0][t] = red[0][t] + red[0][t + 128];
        red[1][t] = red[1][t] + red[1][t + 128];
    }
    __syncthreads();
    if (t < 64) {
        float real = red[0][2 * t] + red[0][2 * t + 1];
        float imag = red[1][2 * t] + red[1][2 * t + 1];
        atomicAdd(&realg[t], real);
        atomicAdd(&imagg[t], imag);
    }
}

// ---------------- finalize ----------------------------------------------------
__global__ void finalize_kernel(const float* __restrict__ realg,
                                const float* __restrict__ imagg,
                                const int* __restrict__ count,
                                float* __restrict__ out)
{
    int t = threadIdx.x;
    if (t < NBATCH) {
        float r = realg[t], im = imagg[t];
        float n = fmaxf((float)(*count), 1.0f);
        out[t] = sqrtf(r * r + im * im) / n;
    }
}

extern "C" void kernel_launch(void* const* d_in, const int* in_sizes, int n_in,
                              void* d_out, int out_size, void* d_ws, size_t ws_size,
                              hipStream_t stream) {
    const float* pa   = (const float*)d_in[0];   // phases_a (64, 8192) f32
    const float* pb   = (const float*)d_in[1];   // phases_b (64, 8192) f32
    const int*   mask = (const int*)d_in[2];     // coupling_mask (8192, 8192) i32
    float* out = (float*)d_out;                  // (64,) f32

    char* ws = (char*)d_ws;
    __hip_bfloat16* Xt = (__hip_bfloat16*)ws;
    float* realg = (float*)(ws + CTR_OFF);
    float* imagg = realg + 64;
    int*   count = (int*)(ws + CTR_OFF + 512);
    float* Ppart = (float*)(ws + PPART_OFF);

    // zero real/imag accumulators + count (ws is poisoned 0xAA before each call)
    hipMemsetAsync(ws + CTR_OFF, 0, 4096, stream);

    prep_b_kernel<<<(NBATCH * NB) / 256, 256, 0, stream>>>(pb, Xt);

    dim3 g(NA / BM, SPLITK);
    gemm_kernel<<<g, 256, 0, stream>>>(mask, Xt, Ppart, count);

    reduce_kernel<<<NA / 32, 256, 0, stream>>>(pa, Ppart, realg, imagg);

    finalize_kernel<<<1, 64, 0, stream>>>(realg, imagg, count, out);
}